// Round 1
// baseline (2876.720 us; speedup 1.0000x reference)
//
#include <hip/hip_runtime.h>

// ---------------- problem constants ----------------
#define BATCH    4096
#define HDIM     300      // hidden dim
#define GDIM     1200     // 4*H gate dim
#define TSTEPS   64
#define NKT      19       // K tiles of 32 (K=600 padded to 608)
#define NTILES   75       // N tiles of 16 (1200/16)
#define ASTRIDE  616      // LDS activation row stride (f16): 308 dwords -> max 2-way bank alias
#define CSTRIDE  305      // f32 layer-0 cell-state row stride (odd -> ~2-way alias)
#define OUTSTRIDE (TSTEPS*HDIM)   // 19200
#define ROWS     32       // batch rows per block (2 MFMA row-tiles) -> 128 blocks
#define NWAVES   8

typedef _Float16 half8  __attribute__((ext_vector_type(8)));
typedef float    floatx4 __attribute__((ext_vector_type(4)));

// packed weight stream: elem index = ((l*NTILES + tile)*NKT + kt)*512 + lane*8 + j
//   value = Wcat_l[n][k],  n = tile*16 + (lane&15),  k = kt*32 + (lane>>4)*8 + j
//   n is gate-interleaved packed col: n = 4*hcol + gate  (gate order i,f,g,o)
#define WP_LAYER_ELEMS ((size_t)NTILES * NKT * 512)

__global__ void pack_weights(const float* __restrict__ Wih0, const float* __restrict__ Whh0,
                             const float* __restrict__ Wih1, const float* __restrict__ Whh1,
                             _Float16* __restrict__ wp) {
    int idx = blockIdx.x * 256 + threadIdx.x;
    const int total = 2 * NTILES * NKT * 64;
    if (idx >= total) return;
    int lane  = idx & 63;
    int rest  = idx >> 6;
    int kt    = rest % NKT;
    int rest2 = rest / NKT;
    int tile  = rest2 % NTILES;
    int l     = rest2 / NTILES;
    const float* Wih = l ? Wih1 : Wih0;
    const float* Whh = l ? Whh1 : Whh0;
    int n    = tile * 16 + (lane & 15);
    int hcol = n >> 2, gate = n & 3;
    int jrow = gate * 300 + hcol;
    int k0   = kt * 32 + (lane >> 4) * 8;
    half8 v8;
#pragma unroll
    for (int j = 0; j < 8; ++j) {
        int k = k0 + j;
        float v = 0.f;
        if (k < 300)      v = Wih[jrow * 300 + k];
        else if (k < 600) v = Whh[jrow * 300 + (k - 300)];
        v8[j] = (_Float16)v;
    }
    *(half8*)(wp + (size_t)idx * 8) = v8;
}

__global__ void pack_bias(const float* __restrict__ bih0, const float* __restrict__ bhh0,
                          const float* __restrict__ bih1, const float* __restrict__ bhh1,
                          float* __restrict__ bp) {
    int idx = blockIdx.x * 256 + threadIdx.x;
    if (idx >= 2 * GDIM) return;
    int l = idx / GDIM, n = idx % GDIM;
    int hcol = n >> 2, gate = n & 3;
    int j = gate * 300 + hcol;
    bp[idx] = l ? (bih1[j] + bhh1[j]) : (bih0[j] + bhh0[j]);
}

// native-rcp activations: v_exp_f32 + v_rcp_f32, ~1ulp rcp is far below the 1e-3 tolerance
__device__ __forceinline__ float sigmoid_f(float x) {
    return __builtin_amdgcn_rcpf(1.f + __expf(-x));
}
__device__ __forceinline__ float tanh_f(float x) {
    // (e^2x - 1)/(e^2x + 1) = 1 - 2/(e^2x + 1); e=inf -> rcp=0 -> 1, e=0 -> -1 (no clamp needed)
    float e = __expf(2.f * x);
    return 1.f - 2.f * __builtin_amdgcn_rcpf(e + 1.f);
}

__global__ __launch_bounds__(512, 2)
void lstm_kernel(const float* __restrict__ z, const _Float16* __restrict__ wp,
                 const float* __restrict__ bp, float* __restrict__ out) {
    __shared__ __align__(16) _Float16 A0[ROWS * ASTRIDE];   // layer0 operand [x | h0]
    __shared__ __align__(16) _Float16 A1[ROWS * ASTRIDE];   // layer1 operand [h0n | h1]
    __shared__ float bias_lds[2 * GDIM];
    __shared__ __align__(16) float scratch[NWAVES * 16 * 20];
    __shared__ float Cst0[ROWS * CSTRIDE];                  // layer-0 cell state (layer-1 in regs)

    const int tid  = threadIdx.x;
    const int wave = tid >> 6;
    const int lane = tid & 63;
    const int row0 = blockIdx.x * ROWS;

    // ---- init ----
    for (int i = tid; i < ROWS * ASTRIDE; i += 512) {
        int r = i / ASTRIDE, c = i - r * ASTRIDE;
        A0[i] = (_Float16)((c < HDIM) ? z[(size_t)(row0 + r) * HDIM + c] : 0.f);
        A1[i] = (_Float16)0.f;
    }
    for (int i = tid; i < 2 * GDIM; i += 512) bias_lds[i] = bp[i];
    for (int i = tid; i < ROWS * CSTRIDE; i += 512) Cst0[i] = 0.f;
    __syncthreads();

    const int m    = lane & 15;     // batch row within row-tile
    const int quad = lane >> 4;
    float* myscr = scratch + wave * (16 * 20);
    const int NT  = (82 - wave) / 8;              // col-tiles this wave: 10,10,10,9,...
    const int rot = blockIdx.x % NT;              // de-hotspot L2: XCD-mates start at different tiles
    const size_t tstep = (size_t)8 * NKT * 512;   // weight elems per tile-index step

    // layer-1 cell state in registers; [i] is the (statically unrolled) tile slot, [rt] row-tile
    float c1reg[10][2];
#pragma unroll
    for (int i = 0; i < 10; ++i) { c1reg[i][0] = 0.f; c1reg[i][1] = 0.f; }

    for (int t = 0; t < TSTEPS; ++t) {
        for (int l = 0; l < 2; ++l) {
            _Float16* Asrc = l ? A1 : A0;
            _Float16* Adst = l ? A0 : A1;        // next consumer's x-slot
            const float* bl = bias_lds + l * GDIM;
            const _Float16* wt = wp + (size_t)l * WP_LAYER_ELEMS
                               + (size_t)wave * (NKT * 512) + lane * 8;

            // ---- A fragments for BOTH row-tiles into registers (tile-invariant) ----
            half8 a0[NKT], a1[NKT];
            {
                const _Float16* ar0 = Asrc + m * ASTRIDE + quad * 8;
                const _Float16* ar1 = ar0 + 16 * ASTRIDE;
#pragma unroll
                for (int kt = 0; kt < NKT; ++kt) {
                    a0[kt] = *(const half8*)(ar0 + kt * 32);
                    a1[kt] = *(const half8*)(ar1 + kt * 32);
                }
            }
            __syncthreads();   // B1: all reads of Asrc done -> epilogue may write its h-slot

            // ---- col-tile loop: weights fetched ONCE, used for 2 row-tiles (2x L2 reuse) ----
#pragma unroll
            for (int i = 0; i < 10; ++i) {
                if (i >= NT) break;
                int j = i + rot; if (j >= NT) j -= NT;
                const int tile = wave + 8 * j;
                const _Float16* wc = wt + (size_t)j * tstep;

                floatx4 acc0 = {0.f, 0.f, 0.f, 0.f};
                floatx4 acc1 = {0.f, 0.f, 0.f, 0.f};
                // ping-pong 4-chunk weight window (~8 chunks live, caps VGPR pressure)
                half8 u[4], v[4];
#pragma unroll
                for (int k = 0; k < 4; ++k) u[k] = *(const half8*)(wc + k * 512);
#pragma unroll
                for (int k = 0; k < 4; ++k) v[k] = *(const half8*)(wc + (4 + k) * 512);
#pragma unroll
                for (int k = 0; k < 4; ++k) {
                    acc0 = __builtin_amdgcn_mfma_f32_16x16x32_f16(a0[k], u[k], acc0, 0, 0, 0);
                    acc1 = __builtin_amdgcn_mfma_f32_16x16x32_f16(a1[k], u[k], acc1, 0, 0, 0);
                }
#pragma unroll
                for (int k = 0; k < 4; ++k) u[k] = *(const half8*)(wc + (8 + k) * 512);
#pragma unroll
                for (int k = 0; k < 4; ++k) {
                    acc0 = __builtin_amdgcn_mfma_f32_16x16x32_f16(a0[4 + k], v[k], acc0, 0, 0, 0);
                    acc1 = __builtin_amdgcn_mfma_f32_16x16x32_f16(a1[4 + k], v[k], acc1, 0, 0, 0);
                }
#pragma unroll
                for (int k = 0; k < 4; ++k) v[k] = *(const half8*)(wc + (12 + k) * 512);
#pragma unroll
                for (int k = 0; k < 4; ++k) {
                    acc0 = __builtin_amdgcn_mfma_f32_16x16x32_f16(a0[8 + k], u[k], acc0, 0, 0, 0);
                    acc1 = __builtin_amdgcn_mfma_f32_16x16x32_f16(a1[8 + k], u[k], acc1, 0, 0, 0);
                }
#pragma unroll
                for (int k = 0; k < 3; ++k) u[k] = *(const half8*)(wc + (16 + k) * 512);
#pragma unroll
                for (int k = 0; k < 4; ++k) {
                    acc0 = __builtin_amdgcn_mfma_f32_16x16x32_f16(a0[12 + k], v[k], acc0, 0, 0, 0);
                    acc1 = __builtin_amdgcn_mfma_f32_16x16x32_f16(a1[12 + k], v[k], acc1, 0, 0, 0);
                }
#pragma unroll
                for (int k = 0; k < 3; ++k) {
                    acc0 = __builtin_amdgcn_mfma_f32_16x16x32_f16(a0[16 + k], u[k], acc0, 0, 0, 0);
                    acc1 = __builtin_amdgcn_mfma_f32_16x16x32_f16(a1[16 + k], u[k], acc1, 0, 0, 0);
                }

                // ---- epilogue: realign gates via per-wave LDS scratch (rt0 then rt1) ----
                const float bn_ = bl[tile * 16 + m];
                const int hcol  = tile * 4 + quad;
#pragma unroll
                for (int r = 0; r < 4; ++r) myscr[(quad * 4 + r) * 20 + m] = acc0[r] + bn_;
                __builtin_amdgcn_wave_barrier();
                floatx4 pg0 = *(const floatx4*)(myscr + m * 20 + quad * 4);
                __builtin_amdgcn_wave_barrier();
#pragma unroll
                for (int r = 0; r < 4; ++r) myscr[(quad * 4 + r) * 20 + m] = acc1[r] + bn_;
                __builtin_amdgcn_wave_barrier();
                floatx4 pg1 = *(const floatx4*)(myscr + m * 20 + quad * 4);
                __builtin_amdgcn_wave_barrier();

                {   // row-tile 0: batch row b = m
                    float ig = sigmoid_f(pg0.x), fg = sigmoid_f(pg0.y);
                    float gg = tanh_f(pg0.z),    og = sigmoid_f(pg0.w);
                    float cold = l ? c1reg[i][0] : Cst0[m * CSTRIDE + hcol];
                    float cn = fg * cold + ig * gg;
                    if (l) c1reg[i][0] = cn; else Cst0[m * CSTRIDE + hcol] = cn;
                    float h = og * tanh_f(cn);
                    Asrc[m * ASTRIDE + 300 + hcol] = (_Float16)h;   // own recurrence (safe post-B1)
                    Adst[m * ASTRIDE + hcol]       = (_Float16)h;   // next consumer's x
                    if (l) out[(size_t)(row0 + m) * OUTSTRIDE + (size_t)t * HDIM + hcol] = h;
                }
                {   // row-tile 1: batch row b = 16 + m
                    float ig = sigmoid_f(pg1.x), fg = sigmoid_f(pg1.y);
                    float gg = tanh_f(pg1.z),    og = sigmoid_f(pg1.w);
                    float cold = l ? c1reg[i][1] : Cst0[(16 + m) * CSTRIDE + hcol];
                    float cn = fg * cold + ig * gg;
                    if (l) c1reg[i][1] = cn; else Cst0[(16 + m) * CSTRIDE + hcol] = cn;
                    float h = og * tanh_f(cn);
                    Asrc[(16 + m) * ASTRIDE + 300 + hcol] = (_Float16)h;
                    Adst[(16 + m) * ASTRIDE + hcol]       = (_Float16)h;
                    if (l) out[(size_t)(row0 + 16 + m) * OUTSTRIDE + (size_t)t * HDIM + hcol] = h;
                }
            }
            __syncthreads();   // B2: this phase's LDS writes visible to next phase's readers
        }
    }
}

extern "C" void kernel_launch(void* const* d_in, const int* in_sizes, int n_in,
                              void* d_out, int out_size, void* d_ws, size_t ws_size,
                              hipStream_t stream) {
    const float* z    = (const float*)d_in[0];
    const float* Wih0 = (const float*)d_in[1];
    const float* Whh0 = (const float*)d_in[2];
    const float* bih0 = (const float*)d_in[3];
    const float* bhh0 = (const float*)d_in[4];
    const float* Wih1 = (const float*)d_in[5];
    const float* Whh1 = (const float*)d_in[6];
    const float* bih1 = (const float*)d_in[7];
    const float* bhh1 = (const float*)d_in[8];
    float* out = (float*)d_out;

    _Float16* wp  = (_Float16*)d_ws;
    float*    bpf = (float*)((char*)d_ws + 2 * WP_LAYER_ELEMS * sizeof(_Float16));

    {
        int total = 2 * NTILES * NKT * 64;
        pack_weights<<<(total + 255) / 256, 256, 0, stream>>>(Wih0, Whh0, Wih1, Whh1, wp);
    }
    pack_bias<<<(2 * GDIM + 255) / 256, 256, 0, stream>>>(bih0, bhh0, bih1, bhh1, bpf);

    lstm_kernel<<<BATCH / ROWS, 512, 0, stream>>>(z, wp, bpf, out);
}